// Round 10
// baseline (382.332 us; speedup 1.0000x reference)
//
#include <hip/hip_runtime.h>
#include <math.h>

#define NB 64
#define NN 207
#define NT 48
#define NF 6
#define NH 64
#define NSEQ (NB*NN)        // 13248 = 828*16
#define NG   (NSEQ/16)      // 828 LSTM blocks of 16 seqs
#define TSTRIDE ((size_t)NSEQ*NH)   // u32 per t-plane of sxp

typedef short bf8_t __attribute__((ext_vector_type(8)));
typedef float f4_t  __attribute__((ext_vector_type(4)));
typedef unsigned short ushort;
typedef unsigned int uint;

__device__ __forceinline__ ushort bf16h(float x){
  uint u = __float_as_uint(x);
  return (ushort)((u + 0x7FFF + ((u>>16)&1)) >> 16);
}
__device__ __forceinline__ float bf16f(ushort h){
  return __uint_as_float((uint)h << 16);
}
__device__ __forceinline__ float fsig(float x){
  return __builtin_amdgcn_rcpf(1.0f + __expf(-x));
}
__device__ __forceinline__ float ftanh(float x){
  x = fminf(15.0f, fmaxf(-15.0f, x));
  float e = __expf(2.0f*x);
  return 1.0f - 2.0f*__builtin_amdgcn_rcpf(e + 1.0f);
}

// interchange: sxp[t][sg][64] u32, each = (bf16_hi<<16)|bf16_lo of h2 (row-major
// == MFMA A-fragment order for 16-seq groups)

// ---------------- GCN v6 (unchanged from round 9): 4 t-planes per block ----------------
#define HW 72
#define XS4 28
#define GCN6_LDS_BYTES (208*HW*2 + (207*XS4 + NF*64 + 64 + 64 + 256 + 256 + 32)*4)

__global__ __launch_bounds__(256, 2) void gcn_kernel(
    const float* __restrict__ x, const float* __restrict__ W1, const float* __restrict__ b1,
    const float* __restrict__ W2, const float* __restrict__ b2, uint* __restrict__ sxp)
{
  extern __shared__ char smraw[];
  ushort* h1b = (ushort*)smraw;            // [208][72] bf16 (row 207 = zero pad)
  float*  xs4 = (float*)(h1b + 208*HW);    // [207][28]
  float*  W1s = xs4 + 207*XS4;             // [6][64]
  float*  b1s = W1s + NF*64;
  float*  b2s = b1s + 64;
  float*  S2_ = b2s + 64;                  // [4][64]
  float*  r1_ = S2_ + 256;                 // [4][64]
  float*  xsA = r1_ + 256;                 // [4][8]

  const int tid = threadIdx.x;
  const int tg = blockIdx.x, b = blockIdx.y;
  const float inv = 1.0f/208.0f;
  const int l = tid & 63;
  const int w = __builtin_amdgcn_readfirstlane(tid >> 6);
  const int col = l & 15, q = l >> 4;
  const int cw = w*16 + col;

  S2_[tid] = 0.f;
  r1_[tid] = 0.f;
  if (tid < 32) xsA[tid] = 0.f;
  if (tid < 72) h1b[207*HW + tid] = 0;

  for (int i=tid;i<NF*64;i+=256) W1s[i]=W1[i];
  if (tid<64){ b1s[tid]=b1[tid]; b2s[tid]=b2[tid]; }
  {
    const float* xb = x + (size_t)b*NN*(NT*NF) + (size_t)tg*24;
    for (int i=tid; i<207*6; i+=256){
      int n = i/6, c = (i - n*6)*4;
      *(float4*)&xs4[n*XS4 + c] = *(const float4*)&xb[(size_t)n*(NT*NF) + c];
    }
  }
  __syncthreads();

  if (tid < 192){
    int tt = tid/48, rem = tid - tt*48, f = rem>>3, p = rem&7;
    float ps = 0.f;
    for (int n=p; n<NN; n+=8) ps += xs4[n*XS4 + tt*6 + f];
    atomicAdd(&xsA[tt*8+f], ps);
  }

  float wtmp[16];
  #pragma unroll
  for (int kc=0;kc<2;kc++)
    #pragma unroll
    for (int j=0;j<8;j++)
      wtmp[kc*8+j] = W2[(size_t)(kc*32 + q*8 + j)*64 + cw];
  bf8_t B2[2];
  #pragma unroll
  for (int kc=0;kc<2;kc++){
    bf8_t ph;
    #pragma unroll
    for (int j=0;j<8;j++) ph[j] = (short)bf16h(wtmp[kc*8+j]);
    B2[kc]=ph;
  }
  __syncthreads();

  const int ht4 = (tid & 15) * 4;
  const int nti = tid >> 4;

  #pragma unroll 1
  for (int tt=0; tt<4; tt++){
    const int t = tg*4 + tt;
    {
      float s1v[4];
      #pragma unroll
      for (int j=0;j<4;j++){
        float a = 0.f;
        #pragma unroll
        for (int f=0;f<NF;f++) a += xsA[tt*8+f]*W1s[f*64 + ht4 + j];
        s1v[j] = a;
      }
      float cs0=0.f, cs1=0.f, cs2=0.f, cs3=0.f;
      #pragma unroll 1
      for (int p=0;p<4;p++){
        int nt = p*16 + nti;
        if (nt < 52){
          #pragma unroll
          for (int i=0;i<4;i++){
            int n = 4*nt+i;
            if (n < NN){
              float a0=0.f,a1=0.f,a2=0.f,a3=0.f;
              #pragma unroll
              for (int f=0;f<NF;f++){
                float xv = xs4[n*XS4 + tt*6 + f];
                float4 wv = *(const float4*)&W1s[f*64 + ht4];
                a0+=xv*wv.x; a1+=xv*wv.y; a2+=xv*wv.z; a3+=xv*wv.w;
              }
              float v0=(a0+s1v[0])*inv + b1s[ht4+0]; v0 = v0>0.f?v0:0.f;
              float v1=(a1+s1v[1])*inv + b1s[ht4+1]; v1 = v1>0.f?v1:0.f;
              float v2=(a2+s1v[2])*inv + b1s[ht4+2]; v2 = v2>0.f?v2:0.f;
              float v3=(a3+s1v[3])*inv + b1s[ht4+3]; v3 = v3>0.f?v3:0.f;
              ushort4 hi;
              hi.x=bf16h(v0); hi.y=bf16h(v1); hi.z=bf16h(v2); hi.w=bf16h(v3);
              *(ushort4*)&h1b[n*HW + ht4] = hi;
              cs0+=v0; cs1+=v1; cs2+=v2; cs3+=v3;
            }
          }
        }
      }
      atomicAdd(&r1_[tt*64+ht4+0], cs0);
      atomicAdd(&r1_[tt*64+ht4+1], cs1);
      atomicAdd(&r1_[tt*64+ht4+2], cs2);
      atomicAdd(&r1_[tt*64+ht4+3], cs3);
    }
    __syncthreads();

    {
      int h = tid & 63, pp = tid >> 6;
      float ps = 0.f;
      #pragma unroll
      for (int k=0;k<16;k++) ps += r1_[tt*64+pp*16+k]*W2[(size_t)(pp*16+k)*64 + h];
      atomicAdd(&S2_[tt*64+h], ps);
    }

    f4_t acc[13];
    #pragma unroll
    for (int mt=0;mt<13;mt++){ f4_t z; z[0]=0.f;z[1]=0.f;z[2]=0.f;z[3]=0.f; acc[mt]=z; }
    #pragma unroll 2
    for (int mt=0;mt<13;mt++){
      #pragma unroll
      for (int kc=0;kc<2;kc++){
        bf8_t ah = *(const bf8_t*)(h1b + (mt*16+col)*HW + kc*32 + q*8);
        acc[mt] = __builtin_amdgcn_mfma_f32_16x16x32_bf16(ah, B2[kc], acc[mt], 0,0,0);
      }
    }
    __syncthreads();

    {
      const float s2v = S2_[tt*64+cw], b2v = b2s[cw];
      uint* obase = sxp + ((size_t)t*NSEQ + (size_t)b*NN)*NH + cw;
      #pragma unroll
      for (int mt=0;mt<13;mt++){
        #pragma unroll
        for (int r=0;r<4;r++){
          int n = mt*16 + q*4 + r;
          if (n < NN){
            float v = (acc[mt][r] + s2v)*inv + b2v;
            v = v>0.f ? v : 0.f;
            ushort hb = bf16h(v);
            ushort lb = bf16h(v - bf16f(hb));
            obase[(size_t)n*NH] = ((uint)hb<<16) | (uint)lb;
          }
        }
      }
    }
  }
}

// ---------------- LSTM v9: 8-wave blocks, 64-VGPR B-frags, LDS gate exchange ----------------
// 828 blocks x 512 threads (8 waves). Wave w owns gate rows [32w, 32w+32)
// (2 consecutive 16x16 tiles) -> B-frags = 64 VGPR. Gates go through a
// stride-20 LDS f32 plane (b128 writes, 16B-aligned); every thread updates
// 2 (seq,dim) c-states. 2 barriers/step. x(t+1) global uint2 issued before
// the MFMA phase (latency hidden), written to LDS in phase B.
#define GS 20   // gate plane stride (floats): 80 B rows, 16B-aligned b128 stores

__global__ __launch_bounds__(512, 2) void lstm9_kernel(
    const uint* __restrict__ sxp,
    const float* __restrict__ Wih, const float* __restrict__ Whh,
    const float* __restrict__ bih, const float* __restrict__ bhh,
    const float* __restrict__ Wfc, const float* __restrict__ bfc, float* __restrict__ out)
{
  __shared__ float G[256*GS];       // 20480 B gate plane [gate row][20]
  __shared__ uint hbuf[16*68];      // 4352 B packed h [s][68]
  __shared__ uint xbuf[16*68];      // 4352 B packed x [s][68]

  const int tid = threadIdx.x;
  const int l = tid & 63;
  const int w = __builtin_amdgcn_readfirstlane(tid >> 6);   // 0..7
  const int col = l & 15, q = l >> 4;
  const int blk = blockIdx.x;
  const int g0 = (2*w)*16 + col;    // first owned gate row
  const int g1 = g0 + 16;

  // B fragments: [tile][mat*2+kk]; rows r = g0 / g1; 64 VGPRs total
  bf8_t Bh[2][4], Bl[2][4];
  #pragma unroll
  for (int mat=0; mat<2; mat++){
    const float* W = mat ? Whh : Wih;
    #pragma unroll
    for (int ti=0; ti<2; ti++){
      const int row = g0 + ti*16;
      #pragma unroll
      for (int kk=0; kk<2; kk++){
        const float* wp = W + (size_t)row*64 + kk*32 + q*8;
        bf8_t ph, pl;
        #pragma unroll
        for (int j=0;j<8;j++){
          float wv = wp[j];
          ushort hb = bf16h(wv);
          ph[j] = (short)hb;
          pl[j] = (short)bf16h(wv - bf16f(hb));
        }
        Bh[ti][mat*2+kk] = ph;
        Bl[ti][mat*2+kk] = pl;
      }
    }
  }
  const float bias0 = bih[g0] + bhh[g0];
  const float bias1 = bih[g1] + bhh[g1];

  // update-role constants: pairs (s_p, d0p) and (s_p, d0p+32)
  const int s_p = tid & 15;
  const int d0p = tid >> 4;          // [0,32)
  float c0 = 0.f, c1 = 0.f;

  for (int i=tid; i<16*68; i+=512) hbuf[i] = 0;
  {  // stage x(0): uint2 per thread, coalesced
    const uint2 px = *(const uint2*)(sxp + (size_t)blk*1024 + tid*2);
    const int s = (tid*2)>>6, dd = (tid*2)&63;
    *(uint2*)&xbuf[s*68 + dd] = px;
  }
  const int abase = col*68;          // A-frag read base (+ kk*32 + q*8)
  __syncthreads();

  #pragma unroll 1
  for (int t=0; t<NT; t++){
    // early global load of x(t+1) — consumed after barrier1
    uint2 px;
    const bool pf = (t+1 < NT);
    if (pf) px = *(const uint2*)(sxp + (size_t)(t+1)*TSTRIDE + (size_t)blk*1024 + tid*2);

    f4_t acc0, acc1;
    acc0[0]=bias0; acc0[1]=bias0; acc0[2]=bias0; acc0[3]=bias0;
    acc1[0]=bias1; acc1[1]=bias1; acc1[2]=bias1; acc1[3]=bias1;

    #pragma unroll
    for (int kk=0; kk<2; kk++){   // x part
      const uint* xp = &xbuf[abase + kk*32 + q*8];
      uint4 a = *(const uint4*)xp, b = *(const uint4*)(xp+4);
      bf8_t xh, xl;
      uint u[8];
      u[0]=a.x;u[1]=a.y;u[2]=a.z;u[3]=a.w;u[4]=b.x;u[5]=b.y;u[6]=b.z;u[7]=b.w;
      #pragma unroll
      for (int j=0;j<8;j++){ xh[j]=(short)(u[j]>>16); xl[j]=(short)(u[j]&0xffff); }
      acc0 = __builtin_amdgcn_mfma_f32_16x16x32_bf16(xh, Bh[0][kk], acc0, 0,0,0);
      acc0 = __builtin_amdgcn_mfma_f32_16x16x32_bf16(xl, Bh[0][kk], acc0, 0,0,0);
      acc0 = __builtin_amdgcn_mfma_f32_16x16x32_bf16(xh, Bl[0][kk], acc0, 0,0,0);
      acc1 = __builtin_amdgcn_mfma_f32_16x16x32_bf16(xh, Bh[1][kk], acc1, 0,0,0);
      acc1 = __builtin_amdgcn_mfma_f32_16x16x32_bf16(xl, Bh[1][kk], acc1, 0,0,0);
      acc1 = __builtin_amdgcn_mfma_f32_16x16x32_bf16(xh, Bl[1][kk], acc1, 0,0,0);
    }
    #pragma unroll
    for (int kk=0; kk<2; kk++){   // h part
      const uint* hp = &hbuf[abase + kk*32 + q*8];
      uint4 a = *(const uint4*)hp, b = *(const uint4*)(hp+4);
      bf8_t hh, hl;
      uint u[8];
      u[0]=a.x;u[1]=a.y;u[2]=a.z;u[3]=a.w;u[4]=b.x;u[5]=b.y;u[6]=b.z;u[7]=b.w;
      #pragma unroll
      for (int j=0;j<8;j++){ hh[j]=(short)(u[j]>>16); hl[j]=(short)(u[j]&0xffff); }
      acc0 = __builtin_amdgcn_mfma_f32_16x16x32_bf16(hh, Bh[0][2+kk], acc0, 0,0,0);
      acc0 = __builtin_amdgcn_mfma_f32_16x16x32_bf16(hl, Bh[0][2+kk], acc0, 0,0,0);
      acc0 = __builtin_amdgcn_mfma_f32_16x16x32_bf16(hh, Bl[0][2+kk], acc0, 0,0,0);
      acc1 = __builtin_amdgcn_mfma_f32_16x16x32_bf16(hh, Bh[1][2+kk], acc1, 0,0,0);
      acc1 = __builtin_amdgcn_mfma_f32_16x16x32_bf16(hl, Bh[1][2+kk], acc1, 0,0,0);
      acc1 = __builtin_amdgcn_mfma_f32_16x16x32_bf16(hh, Bl[1][2+kk], acc1, 0,0,0);
    }
    // gate store: C f4 = 4 consecutive seqs for gate row g  -> G[g][q*4..+3]
    *(f4_t*)&G[g0*GS + q*4] = acc0;
    *(f4_t*)&G[g1*GS + q*4] = acc1;
    __syncthreads();

    // ---- phase B: update 2 c-states + stage x(t+1) ----
    {
      float gi = G[(d0p     )*GS + s_p];
      float gf = G[(d0p+  64)*GS + s_p];
      float gg = G[(d0p+ 128)*GS + s_p];
      float go = G[(d0p+ 192)*GS + s_p];
      float cc0 = fsig(gf)*c0 + fsig(gi)*ftanh(gg);
      c0 = cc0;
      float hv0 = fsig(go)*ftanh(cc0);

      const int d1p = d0p + 32;
      gi = G[(d1p     )*GS + s_p];
      gf = G[(d1p+  64)*GS + s_p];
      gg = G[(d1p+ 128)*GS + s_p];
      go = G[(d1p+ 192)*GS + s_p];
      float cc1 = fsig(gf)*c1 + fsig(gi)*ftanh(gg);
      c1 = cc1;
      float hv1 = fsig(go)*ftanh(cc1);

      if (t != NT-1){
        ushort hb0 = bf16h(hv0);
        hbuf[s_p*68 + d0p] = ((uint)hb0<<16) | (uint)bf16h(hv0 - bf16f(hb0));
        ushort hb1 = bf16h(hv1);
        hbuf[s_p*68 + d1p] = ((uint)hb1<<16) | (uint)bf16h(hv1 - bf16f(hb1));
      } else {
        hbuf[s_p*68 + d0p] = __float_as_uint(hv0);
        hbuf[s_p*68 + d1p] = __float_as_uint(hv1);
      }
    }
    if (pf){
      const int s = (tid*2)>>6, dd = (tid*2)&63;
      *(uint2*)&xbuf[s*68 + dd] = px;
    }
    __syncthreads();
  }

  // epilogue: out[seq] = h_T . W_fc + b_fc  (final h fp32 in hbuf)
  if (tid < 16){
    float a = bfc[0];
    #pragma unroll 8
    for (int k=0;k<64;k++) a += __uint_as_float(hbuf[tid*68 + k]) * Wfc[k];
    out[blk*16 + tid] = a;
  }
}

extern "C" void kernel_launch(void* const* d_in, const int* in_sizes, int n_in,
                              void* d_out, int out_size, void* d_ws, size_t ws_size,
                              hipStream_t stream) {
  const float* x   = (const float*)d_in[0];
  // d_in[1], d_in[2] (N1, N2): structurally dead — sigmoid(N1@N2)>0 is all-ones.
  const float* W1  = (const float*)d_in[3];
  const float* b1  = (const float*)d_in[4];
  const float* W2  = (const float*)d_in[5];
  const float* b2  = (const float*)d_in[6];
  const float* Wih = (const float*)d_in[7];
  const float* Whh = (const float*)d_in[8];
  const float* bih = (const float*)d_in[9];
  const float* bhh = (const float*)d_in[10];
  const float* Wfc = (const float*)d_in[11];
  const float* bfc = (const float*)d_in[12];

  uint*  sxp = (uint*)d_ws;    // [48][13248][64] packed (bf16hi<<16)|bf16lo = 162.8 MB
  float* out = (float*)d_out;

  hipFuncSetAttribute((const void*)gcn_kernel, hipFuncAttributeMaxDynamicSharedMemorySize, GCN6_LDS_BYTES);

  gcn_kernel<<<dim3(NT/4, NB), 256, GCN6_LDS_BYTES, stream>>>(x, W1, b1, W2, b2, sxp);
  lstm9_kernel<<<NG, 512, 0, stream>>>(sxp, Wih, Whh, bih, bhh, Wfc, bfc, out);
}